// Round 1
// baseline (1034.427 us; speedup 1.0000x reference)
//
#include <hip/hip_runtime.h>

// Kalman filter: G=1024 groups, T=200 steps, S=16, M=4, fp32.
// One block (256 threads) per group; state (mean, cov) in LDS; sequential
// loop over T. All per-step matmuls are one-output-per-thread with 16-MAC
// dot products. (I-KH)cov folded to cov - K*HP (4 MACs). 4x4 solve via
// cofactor adjugate. Inputs prefetched one step ahead into registers.

constexpr int Gc = 1024;
constexpr int Tc = 200;
constexpr int Sc = 16;   // state dim
constexpr int Mc = 4;    // obs dim

__global__ __launch_bounds__(256, 4)
void kalman_kernel(const float* __restrict__ y,        // [G,T,M]
                   const float* __restrict__ F,        // [G,T,S,S]
                   const float* __restrict__ H,        // [G,T,M,S]
                   const float* __restrict__ Q,        // [G,T,S,S]
                   const float* __restrict__ R,        // [G,T,M,M]
                   const float* __restrict__ initMean, // [G,S]
                   const float* __restrict__ initCov,  // [G,S,S]
                   float* __restrict__ out)
{
    const int g   = blockIdx.x;
    const int tid = threadIdx.x;
    const int i   = tid >> 4;   // 0..15
    const int k   = tid & 15;   // 0..15

    // padded leading dims (+1) -> stride-17 column reads are bank-conflict-free
    __shared__ float sMean[Sc];
    __shared__ float sMeanU[Sc];
    __shared__ float sMeanP[Sc];
    __shared__ float sCov [Sc][Sc + 1];
    __shared__ float sCovU[Sc][Sc + 1];
    __shared__ float sTmp [Sc][Sc + 1];
    __shared__ float sF   [Sc][Sc + 1];
    __shared__ float sQ   [Sc * Sc];
    __shared__ float sH   [Mc][Sc + 1];
    __shared__ float sHP  [Mc][Sc + 1];
    __shared__ float sR   [Mc * Mc];
    __shared__ float sS   [Mc * Mc];   // Ssig = HP H' + R
    __shared__ float sCof [Mc * Mc];   // cofactors of Ssig
    __shared__ float sK   [Sc * Mc];   // K[s][m]
    __shared__ float sY   [Mc];
    __shared__ float sResid[Mc];

    const size_t gT = (size_t)g * Tc;

    // output layout: [means | covs | R | H], each flat [G,T,...]
    float* outMeans = out;
    float* outCovs  = out + (size_t)Gc * Tc * Sc;
    float* outR     = outCovs + (size_t)Gc * Tc * Sc * Sc;
    float* outH     = outR + (size_t)Gc * Tc * Mc * Mc;

    // ---- init state ----
    if (tid < Sc) sMean[tid] = initMean[g * Sc + tid];
    sCov[i][k] = initCov[g * Sc * Sc + tid];

    // ---- preload t=0 inputs into registers ----
    float rF = F[gT * 256 + tid];
    float rQ = Q[gT * 256 + tid];
    float rH = (tid < 64) ? H[gT * 64 + tid] : 0.f;
    float rR = (tid < 16) ? R[gT * 16 + tid] : 0.f;
    float rY = (tid < 4)  ? y[gT * 4  + tid] : 0.f;

    __syncthreads();

    for (int t = 0; t < Tc; ++t) {
        const size_t gt = gT + t;

        // ---- phase A: emit outputs (pre-update state) + passthrough ----
        if (tid < Sc) outMeans[gt * Sc + tid] = sMean[tid];
        outCovs[gt * 256 + tid] = sCov[i][k];
        if (tid < 64) outH[gt * 64 + tid] = rH;
        if (tid < 16) outR[gt * 16 + tid] = rR;

        if (t == Tc - 1) break;   // uniform branch; no further compute needed

        // stage current step's inputs into LDS
        sF[i][k] = rF;
        sQ[tid]  = rQ;
        if (tid < 64) sH[tid >> 4][tid & 15] = rH;
        if (tid < 16) sR[tid] = rR;
        if (tid < 4)  sY[tid] = rY;

        // prefetch next step (latency hidden under this step's compute)
        {
            const size_t gt1 = gt + 1;
            rF = F[gt1 * 256 + tid];
            rQ = Q[gt1 * 256 + tid];
            if (tid < 64) rH = H[gt1 * 64 + tid];
            if (tid < 16) rR = R[gt1 * 16 + tid];
            if (tid < 4)  rY = y[gt1 * 4 + tid];
        }
        __syncthreads();

        // ---- phase B: HP = H*cov (tid<64); resid = y - H*mean (tid 64..67) ----
        if (tid < 64) {
            const int m = tid >> 4, s = tid & 15;
            float acc = 0.f;
            #pragma unroll
            for (int n = 0; n < Sc; ++n) acc += sH[m][n] * sCov[n][s];
            sHP[m][s] = acc;
        } else if (tid < 68) {
            const int m = tid - 64;
            float acc = sY[m];
            #pragma unroll
            for (int n = 0; n < Sc; ++n) acc -= sH[m][n] * sMean[n];
            sResid[m] = acc;
        }
        __syncthreads();

        // ---- phase C: Ssig = HP*H' + R (tid<16) ----
        if (tid < 16) {
            const int m = tid >> 2, kk = tid & 3;
            float acc = sR[tid];
            #pragma unroll
            for (int n = 0; n < Sc; ++n) acc += sHP[m][n] * sH[kk][n];
            sS[tid] = acc;
        }
        __syncthreads();

        // ---- phase D: cofactors of 4x4 Ssig (tid<16) ----
        if (tid < 16) {
            const int m = tid >> 2, kk = tid & 3;
            const int r0 = (m == 0) ? 1 : 0;
            const int r1 = (m <= 1) ? 2 : 1;
            const int r2 = (m <= 2) ? 3 : 2;
            const int c0 = (kk == 0) ? 1 : 0;
            const int c1 = (kk <= 1) ? 2 : 1;
            const int c2 = (kk <= 2) ? 3 : 2;
            const float a = sS[r0*4+c0], b = sS[r0*4+c1], c = sS[r0*4+c2];
            const float d = sS[r1*4+c0], e = sS[r1*4+c1], f = sS[r1*4+c2];
            const float p = sS[r2*4+c0], q = sS[r2*4+c1], r = sS[r2*4+c2];
            const float det3 = a*(e*r - f*q) - b*(d*r - f*p) + c*(d*q - e*p);
            sCof[tid] = ((m + kk) & 1) ? -det3 : det3;
        }
        __syncthreads();

        // ---- phase E: K = (Ssig^-1 HP)' (tid<64) ----
        if (tid < 64) {
            const int s = tid >> 2, m = tid & 3;
            const float det = sS[0]*sCof[0] + sS[1]*sCof[1]
                            + sS[2]*sCof[2] + sS[3]*sCof[3];
            // X[m][s] = (1/det) * sum_k cof[k][m] * HP[k][s]; K[s][m] = X[m][s]
            const float num = sCof[0*4+m]*sHP[0][s] + sCof[1*4+m]*sHP[1][s]
                            + sCof[2*4+m]*sHP[2][s] + sCof[3*4+m]*sHP[3][s];
            sK[s*4+m] = num / det;
        }
        __syncthreads();

        // ---- phase F: covU = cov - K*HP (all); meanU (tid 192..207) ----
        {
            float acc = sCov[i][k];
            #pragma unroll
            for (int m = 0; m < Mc; ++m) acc -= sK[i*4+m] * sHP[m][k];
            sCovU[i][k] = acc;
        }
        if (tid >= 192 && tid < 208) {
            const int s = tid - 192;
            float acc = sMean[s];
            #pragma unroll
            for (int m = 0; m < Mc; ++m) acc += sK[s*4+m] * sResid[m];
            sMeanU[s] = acc;
        }
        __syncthreads();

        // ---- phase G: tmp = F*covU (all); meanP = F*meanU (tid 192..207) ----
        {
            float acc = 0.f;
            #pragma unroll
            for (int j = 0; j < Sc; ++j) acc += sF[i][j] * sCovU[j][k];
            sTmp[i][k] = acc;
        }
        if (tid >= 192 && tid < 208) {
            const int s = tid - 192;
            float acc = 0.f;
            #pragma unroll
            for (int j = 0; j < Sc; ++j) acc += sF[s][j] * sMeanU[j];
            sMeanP[s] = acc;
        }
        __syncthreads();

        // ---- phase H: cov = tmp*F' + Q (all); mean = meanP ----
        {
            float acc = sQ[tid];
            #pragma unroll
            for (int kk = 0; kk < Sc; ++kk) acc += sTmp[i][kk] * sF[k][kk];
            sCov[i][k] = acc;
        }
        if (tid >= 192 && tid < 208) sMean[tid - 192] = sMeanP[tid - 192];
        __syncthreads();
    }
}

extern "C" void kernel_launch(void* const* d_in, const int* in_sizes, int n_in,
                              void* d_out, int out_size, void* d_ws, size_t ws_size,
                              hipStream_t stream) {
    const float* y        = (const float*)d_in[0];
    const float* F        = (const float*)d_in[1];
    const float* H        = (const float*)d_in[2];
    const float* Q        = (const float*)d_in[3];
    const float* R        = (const float*)d_in[4];
    const float* initMean = (const float*)d_in[5];
    const float* initCov  = (const float*)d_in[6];
    float* out = (float*)d_out;

    kalman_kernel<<<Gc, 256, 0, stream>>>(y, F, H, Q, R, initMean, initCov, out);
}